// Round 1
// baseline (2219.123 us; speedup 1.0000x reference)
//
#include <hip/hip_runtime.h>

#define N_NODES 100000
#define G_GRAPHS 256
#define IN_F 162
#define HID 128
#define R_REL 5
#define L_LAYERS 2

#define BM 64
#define BK 16

__global__ void zero_i32(int* p, int n) {
    int i = blockIdx.x * blockDim.x + threadIdx.x;
    if (i < n) p[i] = 0;
}

__global__ void count_edges(const int* __restrict__ ei, int* __restrict__ cnt, int E) {
    int e = blockIdx.x * blockDim.x + threadIdx.x;
    if (e < E) atomicAdd(&cnt[ei[E + e]], 1);
}

__global__ void inv_counts(const int* __restrict__ cnt, float* __restrict__ inv, int n) {
    int i = blockIdx.x * blockDim.x + threadIdx.x;
    if (i < n) inv[i] = 1.0f / (float)max(cnt[i], 1);
}

// C[M x 128] = A[M x K] @ W[K x 128] (+ bias), row-major everywhere.
__global__ __launch_bounds__(256)
void gemm_k(const float* __restrict__ A, const float* __restrict__ W,
            const float* __restrict__ bias, float* __restrict__ C,
            int M, int K) {
    __shared__ float As[BM][BK];
    __shared__ float Bs[BK][HID];
    int tid = threadIdx.x;
    int row0 = blockIdx.x * BM;
    int tx = tid & 31;   // col quad: cols 4*tx .. 4*tx+3
    int ty = tid >> 5;   // row group: rows ty*8 .. ty*8+7

    float acc[8][4];
    if (bias) {
        float4 b4 = *(const float4*)&bias[tx * 4];
        #pragma unroll
        for (int r = 0; r < 8; r++) {
            acc[r][0] = b4.x; acc[r][1] = b4.y; acc[r][2] = b4.z; acc[r][3] = b4.w;
        }
    } else {
        #pragma unroll
        for (int r = 0; r < 8; r++)
            #pragma unroll
            for (int j = 0; j < 4; j++) acc[r][j] = 0.0f;
    }

    for (int k0 = 0; k0 < K; k0 += BK) {
        // Stage A tile: 64 rows x 16 k (guarded)
        int base = tid * 4;
        #pragma unroll
        for (int i = 0; i < 4; i++) {
            int idx = base + i;
            int r = idx >> 4, kk = idx & 15;
            int row = row0 + r, k = k0 + kk;
            As[r][kk] = (row < M && k < K) ? A[(size_t)row * K + k] : 0.0f;
        }
        // Stage B tile: 16 k x 128 cols (float4, guarded on k)
        #pragma unroll
        for (int i = 0; i < 2; i++) {
            int f4 = tid + i * 256;
            int e0 = f4 * 4;
            int kk = e0 >> 7, cc = e0 & 127;
            int k = k0 + kk;
            float4 v = make_float4(0.f, 0.f, 0.f, 0.f);
            if (k < K) v = *(const float4*)&W[(size_t)k * HID + cc];
            *(float4*)&Bs[kk][cc] = v;
        }
        __syncthreads();
        #pragma unroll
        for (int kk = 0; kk < BK; kk++) {
            float4 bv = *(const float4*)&Bs[kk][tx * 4];
            #pragma unroll
            for (int r = 0; r < 8; r++) {
                float a = As[ty * 8 + r][kk];
                acc[r][0] += a * bv.x;
                acc[r][1] += a * bv.y;
                acc[r][2] += a * bv.z;
                acc[r][3] += a * bv.w;
            }
        }
        __syncthreads();
    }

    #pragma unroll
    for (int r = 0; r < 8; r++) {
        int row = row0 + ty * 8 + r;
        if (row < M) {
            float4 v = make_float4(acc[r][0], acc[r][1], acc[r][2], acc[r][3]);
            *(float4*)&C[(size_t)row * HID + tx * 4] = v;
        }
    }
}

// acc[dst] += y[src] * inv_cnt[dst], per edge, 128 features.
__global__ __launch_bounds__(256)
void scatter_edges(const float* __restrict__ y, const int* __restrict__ ei,
                   const float* __restrict__ invc, float* __restrict__ acc, int E) {
    int idx = blockIdx.x * 256 + threadIdx.x;
    int e = idx >> 7, c = idx & 127;
    if (e < E) {
        int s = ei[e], d = ei[E + e];
        float w = invc[d];
        atomicAdd(&acc[(size_t)d * HID + c], y[(size_t)s * HID + c] * w);
    }
}

__global__ void relu_k(float* p, int n4) {
    int i = blockIdx.x * blockDim.x + threadIdx.x;
    if (i < n4) {
        float4 v = ((float4*)p)[i];
        v.x = fmaxf(v.x, 0.f); v.y = fmaxf(v.y, 0.f);
        v.z = fmaxf(v.z, 0.f); v.w = fmaxf(v.w, 0.f);
        ((float4*)p)[i] = v;
    }
}

__device__ int lower_bound_i(const int* a, int n, int v) {
    int lo = 0, hi = n;
    while (lo < hi) {
        int mid = (lo + hi) >> 1;
        if (a[mid] < v) lo = mid + 1; else hi = mid;
    }
    return lo;
}

// One block per graph: batch is sorted, binary-search range, mean-pool, 3-layer MLP.
__global__ __launch_bounds__(128)
void readout_mlp(const float* __restrict__ h, const int* __restrict__ batch,
                 const float* __restrict__ Wc1, const float* __restrict__ bc1,
                 const float* __restrict__ Wc2, const float* __restrict__ bc2,
                 const float* __restrict__ Wc3, const float* __restrict__ bc3,
                 float* __restrict__ out) {
    int g = blockIdx.x;
    int c = threadIdx.x;
    __shared__ int range[2];
    if (c == 0) range[0] = lower_bound_i(batch, N_NODES, g);
    if (c == 1) range[1] = lower_bound_i(batch, N_NODES, g + 1);
    __syncthreads();
    int s = range[0], e = range[1];
    float sum = 0.0f;
    for (int i = s; i < e; i++) sum += h[(size_t)i * HID + c];
    __shared__ float row[HID], h1[HID], h2[HID];
    row[c] = sum / fmaxf((float)(e - s), 1.0f);
    __syncthreads();
    float acc = bc1[c];
    for (int k = 0; k < HID; k++) acc += row[k] * Wc1[k * HID + c];
    h1[c] = fmaxf(acc, 0.f);
    __syncthreads();
    acc = bc2[c];
    for (int k = 0; k < HID; k++) acc += h1[k] * Wc2[k * HID + c];
    h2[c] = fmaxf(acc, 0.f);
    __syncthreads();
    float t = h2[c] * Wc3[c];
    for (int off = 32; off > 0; off >>= 1) t += __shfl_down(t, off, 64);
    __shared__ float part[2];
    if ((c & 63) == 0) part[c >> 6] = t;
    __syncthreads();
    if (c == 0) out[g] = part[0] + part[1] + bc3[0];
}

extern "C" void kernel_launch(void* const* d_in, const int* in_sizes, int n_in,
                              void* d_out, int out_size, void* d_ws, size_t ws_size,
                              hipStream_t stream) {
    const float* X     = (const float*)d_in[0];
    const int*   batch = (const int*)d_in[1];
    const int*   ei[R_REL];
    for (int r = 0; r < R_REL; r++) ei[r] = (const int*)d_in[2 + r];
    const float* W0    = (const float*)d_in[7];
    const float* root0 = (const float*)d_in[8];
    const float* b0    = (const float*)d_in[9];
    const float* Wl    = (const float*)d_in[10];
    const float* rootl = (const float*)d_in[11];
    const float* bl    = (const float*)d_in[12];
    const float* Wc1   = (const float*)d_in[13];
    const float* bc1   = (const float*)d_in[14];
    const float* Wc2   = (const float*)d_in[15];
    const float* bc2   = (const float*)d_in[16];
    const float* Wc3   = (const float*)d_in[17];
    const float* bc3   = (const float*)d_in[18];
    int E = in_sizes[2] / 2;

    // Workspace layout
    float* ws   = (float*)d_ws;
    float* h0   = ws;                                   // N*HID
    float* h1   = h0 + (size_t)N_NODES * HID;           // N*HID
    float* y    = h1 + (size_t)N_NODES * HID;           // N*HID
    float* invc = y + (size_t)N_NODES * HID;            // R*N
    int*   cnt  = (int*)(invc + (size_t)R_REL * N_NODES); // R*N ints

    // Per-relation in-degree -> 1/max(cnt,1)
    int cn = R_REL * N_NODES;
    zero_i32<<<(cn + 255) / 256, 256, 0, stream>>>(cnt, cn);
    for (int r = 0; r < R_REL; r++)
        count_edges<<<(E + 255) / 256, 256, 0, stream>>>(ei[r], cnt + (size_t)r * N_NODES, E);
    inv_counts<<<(cn + 255) / 256, 256, 0, stream>>>(cnt, invc, cn);

    int gemm_grid = (N_NODES + BM - 1) / BM;
    int sc_grid   = (E * HID + 255) / 256;
    int relu_n4   = N_NODES * HID / 4;
    int relu_grid = (relu_n4 + 255) / 256;

    // Layer 0: x = X (K=162), acc = h0
    gemm_k<<<gemm_grid, 256, 0, stream>>>(X, root0, b0, h0, N_NODES, IN_F);
    for (int r = 0; r < R_REL; r++) {
        gemm_k<<<gemm_grid, 256, 0, stream>>>(X, W0 + (size_t)r * IN_F * HID, nullptr, y, N_NODES, IN_F);
        scatter_edges<<<sc_grid, 256, 0, stream>>>(y, ei[r], invc + (size_t)r * N_NODES, h0, E);
    }
    relu_k<<<relu_grid, 256, 0, stream>>>(h0, relu_n4);

    // Layers 1..L: K = 128, ping-pong h0/h1
    float* xcur = h0;
    float* xnext = h1;
    for (int l = 0; l < L_LAYERS; l++) {
        const float* rt = rootl + (size_t)l * HID * HID;
        const float* bb = bl + (size_t)l * HID;
        gemm_k<<<gemm_grid, 256, 0, stream>>>(xcur, rt, bb, xnext, N_NODES, HID);
        for (int r = 0; r < R_REL; r++) {
            gemm_k<<<gemm_grid, 256, 0, stream>>>(xcur, Wl + ((size_t)l * R_REL + r) * HID * HID,
                                                  nullptr, y, N_NODES, HID);
            scatter_edges<<<sc_grid, 256, 0, stream>>>(y, ei[r], invc + (size_t)r * N_NODES, xnext, E);
        }
        relu_k<<<relu_grid, 256, 0, stream>>>(xnext, relu_n4);
        float* t = xcur; xcur = xnext; xnext = t;
    }

    // Readout + MLP (batch sorted -> binary search per graph, no atomics)
    readout_mlp<<<G_GRAPHS, 128, 0, stream>>>(xcur, batch, Wc1, bc1, Wc2, bc2, Wc3, bc3, (float*)d_out);
}

// Round 2
// 1072.499 us; speedup vs baseline: 2.0691x; 2.0691x over previous
//
#include <hip/hip_runtime.h>

#define N_NODES 100000
#define NPAD    100096      // 782 * 128
#define G_GRAPHS 256
#define IN_F 162
#define KPAD0 192
#define HID 128
#define R_REL 5
#define L_LAYERS 2
#define M5 (R_REL * N_NODES)

typedef __attribute__((ext_vector_type(8))) short bf16x8;
typedef __attribute__((ext_vector_type(4))) float f32x4;

__device__ __forceinline__ short f2bf(float f) {
    union { float f; unsigned u; } v; v.f = f;
    unsigned r = (v.u + 0x7fffu + ((v.u >> 16) & 1u)) >> 16;
    return (short)r;
}
__device__ __forceinline__ float bf2f(unsigned short u) {
    union { unsigned u; float f; } v; v.u = ((unsigned)u) << 16;
    return v.f;
}

// ---------------- CSR build ----------------
__global__ void k_count(const int* e0, const int* e1, const int* e2,
                        const int* e3, const int* e4, int* cnt, int E) {
    int gid = blockIdx.x * 256 + threadIdx.x;
    if (gid >= R_REL * E) return;
    int r = gid / E, e = gid - r * E;
    const int* ei = (r == 0) ? e0 : (r == 1) ? e1 : (r == 2) ? e2 : (r == 3) ? e3 : e4;
    atomicAdd(&cnt[r * N_NODES + ei[E + e]], 1);
}

// block scans 1024 elements (256 thr x 4)
__global__ __launch_bounds__(256) void k_scan1(const int* __restrict__ cnt,
                                               int* __restrict__ off, int* __restrict__ bsum) {
    __shared__ int ts[256];
    int t = threadIdx.x;
    int base = blockIdx.x * 1024 + t * 4;
    int v[4];
    #pragma unroll
    for (int j = 0; j < 4; j++) v[j] = (base + j < M5) ? cnt[base + j] : 0;
    int tsum = v[0] + v[1] + v[2] + v[3];
    ts[t] = tsum; __syncthreads();
    for (int o = 1; o < 256; o <<= 1) {
        int x = (t >= o) ? ts[t - o] : 0;
        __syncthreads();
        ts[t] += x;
        __syncthreads();
    }
    if (t == 255) bsum[blockIdx.x] = ts[255];
    int run = ts[t] - tsum;
    #pragma unroll
    for (int j = 0; j < 4; j++) { if (base + j < M5) off[base + j] = run; run += v[j]; }
}

__global__ __launch_bounds__(512) void k_scan2(int* bsum, int nblk) {
    __shared__ int ts[512];
    int t = threadIdx.x;
    int v = (t < nblk) ? bsum[t] : 0;
    ts[t] = v; __syncthreads();
    for (int o = 1; o < 512; o <<= 1) {
        int x = (t >= o) ? ts[t - o] : 0;
        __syncthreads();
        ts[t] += x;
        __syncthreads();
    }
    if (t < nblk) bsum[t] = ts[t] - v;   // exclusive
}

__global__ void k_scan3(int* __restrict__ off, const int* __restrict__ bsum,
                        int* __restrict__ cur, const int* __restrict__ cnt,
                        float* __restrict__ invc) {
    int i = blockIdx.x * 256 + threadIdx.x;
    if (i >= M5) return;
    int o = off[i] + bsum[i >> 10];
    off[i] = o;
    cur[i] = o;
    invc[i] = 1.0f / (float)max(cnt[i], 1);
}

__global__ void k_fill(const int* e0, const int* e1, const int* e2,
                       const int* e3, const int* e4, int* cur, int* csr, int E) {
    int gid = blockIdx.x * 256 + threadIdx.x;
    if (gid >= R_REL * E) return;
    int r = gid / E, e = gid - r * E;
    const int* ei = (r == 0) ? e0 : (r == 1) ? e1 : (r == 2) ? e2 : (r == 3) ? e3 : e4;
    int src = ei[e], dst = ei[E + e];
    int pos = atomicAdd(&cur[r * N_NODES + dst], 1);
    csr[pos] = src;
}

// ---------------- weight pre-transpose (fp32 -> bf16, [chunk][col][Kpad]) ----------------
__global__ void k_tw0(const float* __restrict__ root0, const float* __restrict__ W0,
                      short* __restrict__ out) {
    int gid = blockIdx.x * 256 + threadIdx.x;   // 6*128*192
    if (gid >= 6 * 128 * KPAD0) return;
    int chunk = gid / (128 * KPAD0);
    int rem = gid - chunk * 128 * KPAD0;
    int col = rem / KPAD0;
    int k = rem - col * KPAD0;
    float v = 0.f;
    if (k < IN_F)
        v = (chunk == 0) ? root0[k * HID + col]
                         : W0[((size_t)(chunk - 1) * IN_F + k) * HID + col];
    out[gid] = f2bf(v);
}

__global__ void k_twl(const float* __restrict__ rootl, const float* __restrict__ Wl,
                      short* __restrict__ out) {
    int gid = blockIdx.x * 256 + threadIdx.x;   // 2*6*128*128
    if (gid >= L_LAYERS * 6 * 128 * HID) return;
    int l = gid / (6 * 128 * HID);
    int rem = gid - l * 6 * 128 * HID;
    int chunk = rem / (128 * HID);
    int rem2 = rem - chunk * 128 * HID;
    int col = rem2 / HID;
    int k = rem2 - col * HID;
    float v = (chunk == 0) ? rootl[((size_t)l * HID + k) * HID + col]
                           : Wl[(((size_t)l * R_REL + (chunk - 1)) * HID + k) * HID + col];
    out[gid] = f2bf(v);
}

// ---------------- MFMA GEMM: Y[chunk][row][128] = A[row][K] @ Wt[chunk][:, K]^T ----------------
// 128x128 tile, 256 threads (4 waves, 2x2), BK=32, 16x16x32 bf16 MFMA.
// LDS stride 40 halfwords (pad +8 -> 2-way bank aliasing only).
template<int KP, bool A_F32>
__global__ __launch_bounds__(256)
void gemm_mfma(const void* __restrict__ Av, const short* __restrict__ Wt,
               unsigned short* __restrict__ Y, int M, int Kreal) {
    __shared__ short As[128 * 40];
    __shared__ short Bs[128 * 40];
    const int tid = threadIdx.x;
    const int row0 = blockIdx.x * 128;
    const int chunk = blockIdx.y;
    const short* Wc = Wt + (size_t)chunk * 128 * KP;
    unsigned short* Yc = Y + (size_t)chunk * NPAD * HID;

    const int lane = tid & 63, wv = tid >> 6;
    const int quad = lane >> 4, l16 = lane & 15;
    const int wr0 = (wv >> 1) * 64, wc0 = (wv & 1) * 64;

    f32x4 acc[4][4];
    #pragma unroll
    for (int i = 0; i < 4; i++)
        #pragma unroll
        for (int j = 0; j < 4; j++) acc[i][j] = (f32x4){0.f, 0.f, 0.f, 0.f};

    for (int k0 = 0; k0 < KP; k0 += 32) {
        // stage A (128 rows x 32 k) and B (128 cols x 32 k), 2 chunks of 8 halfwords each
        #pragma unroll
        for (int tch = 0; tch < 2; tch++) {
            int cidx = tid + tch * 256;          // 0..511
            int row = cidx >> 2;
            int kk8 = (cidx & 3) * 8;
            int grow = row0 + row;
            bf16x8 aval = (bf16x8){0,0,0,0,0,0,0,0};
            if (grow < M) {
                if (A_F32) {
                    const float* Af = (const float*)Av;
                    #pragma unroll
                    for (int j = 0; j < 8; j++) {
                        int k = k0 + kk8 + j;
                        float f = (k < Kreal) ? Af[(size_t)grow * Kreal + k] : 0.f;
                        aval[j] = f2bf(f);
                    }
                } else {
                    aval = *(const bf16x8*)((const short*)Av + (size_t)grow * HID + k0 + kk8);
                }
            }
            *(bf16x8*)&As[row * 40 + kk8] = aval;
            *(bf16x8*)&Bs[row * 40 + kk8] = *(const bf16x8*)&Wc[row * KP + k0 + kk8];
        }
        __syncthreads();
        bf16x8 af[4], bfr[4];
        #pragma unroll
        for (int i = 0; i < 4; i++)
            af[i] = *(const bf16x8*)&As[(wr0 + i * 16 + l16) * 40 + quad * 8];
        #pragma unroll
        for (int j = 0; j < 4; j++)
            bfr[j] = *(const bf16x8*)&Bs[(wc0 + j * 16 + l16) * 40 + quad * 8];
        #pragma unroll
        for (int i = 0; i < 4; i++)
            #pragma unroll
            for (int j = 0; j < 4; j++)
                acc[i][j] = __builtin_amdgcn_mfma_f32_16x16x32_bf16(af[i], bfr[j], acc[i][j], 0, 0, 0);
        __syncthreads();
    }

    #pragma unroll
    for (int i = 0; i < 4; i++) {
        #pragma unroll
        for (int j = 0; j < 4; j++) {
            #pragma unroll
            for (int reg = 0; reg < 4; reg++) {
                int r = row0 + wr0 + i * 16 + quad * 4 + reg;
                int c = wc0 + j * 16 + l16;
                if (r < M) Yc[(size_t)r * HID + c] = (unsigned short)f2bf(acc[i][j][reg]);
            }
        }
    }
}

// ---------------- fused aggregation: root + bias + 5-relation CSR mean, relu, -> bf16 ----------------
__global__ __launch_bounds__(256)
void aggregate(const unsigned short* __restrict__ Y, const int* __restrict__ csr,
               const int* __restrict__ off, const int* __restrict__ cnt,
               const float* __restrict__ invc, const float* __restrict__ bias,
               unsigned short* __restrict__ hout) {
    int gid = blockIdx.x * 256 + threadIdx.x;
    int d = gid >> 7, c = gid & 127;
    if (d >= N_NODES) return;
    float acc = bias[c] + bf2f(Y[(size_t)d * HID + c]);   // chunk 0 = root
    #pragma unroll
    for (int r = 0; r < R_REL; r++) {
        int idx = r * N_NODES + d;
        int s = off[idx], n = cnt[idx];
        const unsigned short* Yr = Y + (size_t)(1 + r) * NPAD * HID;
        float sum = 0.f;
        for (int e = 0; e < n; e++) {
            int src = csr[s + e];
            sum += bf2f(Yr[(size_t)src * HID + c]);
        }
        acc += sum * invc[idx];
    }
    hout[(size_t)d * HID + c] = (unsigned short)f2bf(fmaxf(acc, 0.f));
}

// ---------------- readout: parallel pooling + per-graph MLP ----------------
__global__ __launch_bounds__(128)
void k_pool(const unsigned short* __restrict__ h, const int* __restrict__ batch,
            float* __restrict__ pooled) {
    int c = threadIdx.x;
    int start = blockIdx.x * 128;
    if (start >= N_NODES) return;
    int end = min(start + 128, N_NODES);
    int g = batch[start];
    float s = 0.f;
    for (int i = start; i < end; i++) {
        int gi = batch[i];
        if (gi != g) { atomicAdd(&pooled[g * HID + c], s); s = 0.f; g = gi; }
        s += bf2f(h[(size_t)i * HID + c]);
    }
    atomicAdd(&pooled[g * HID + c], s);
}

__device__ int lower_bound_i(const int* a, int n, int v) {
    int lo = 0, hi = n;
    while (lo < hi) {
        int mid = (lo + hi) >> 1;
        if (a[mid] < v) lo = mid + 1; else hi = mid;
    }
    return lo;
}

__global__ __launch_bounds__(128)
void k_mlp(const float* __restrict__ pooled, const int* __restrict__ batch,
           const float* __restrict__ Wc1, const float* __restrict__ bc1,
           const float* __restrict__ Wc2, const float* __restrict__ bc2,
           const float* __restrict__ Wc3, const float* __restrict__ bc3,
           float* __restrict__ out) {
    int g = blockIdx.x;
    int c = threadIdx.x;
    __shared__ int range[2];
    if (c == 0) range[0] = lower_bound_i(batch, N_NODES, g);
    if (c == 1) range[1] = lower_bound_i(batch, N_NODES, g + 1);
    __syncthreads();
    float denom = fmaxf((float)(range[1] - range[0]), 1.0f);
    __shared__ float row[HID], h1[HID], h2[HID];
    row[c] = pooled[g * HID + c] / denom;
    __syncthreads();
    float acc = bc1[c];
    for (int k = 0; k < HID; k++) acc += row[k] * Wc1[k * HID + c];
    h1[c] = fmaxf(acc, 0.f);
    __syncthreads();
    acc = bc2[c];
    for (int k = 0; k < HID; k++) acc += h1[k] * Wc2[k * HID + c];
    h2[c] = fmaxf(acc, 0.f);
    __syncthreads();
    float t = h2[c] * Wc3[c];
    for (int off = 32; off > 0; off >>= 1) t += __shfl_down(t, off, 64);
    __shared__ float part[2];
    if ((c & 63) == 0) part[c >> 6] = t;
    __syncthreads();
    if (c == 0) out[g] = part[0] + part[1] + bc3[0];
}

// ---------------- launcher ----------------
extern "C" void kernel_launch(void* const* d_in, const int* in_sizes, int n_in,
                              void* d_out, int out_size, void* d_ws, size_t ws_size,
                              hipStream_t stream) {
    const float* X     = (const float*)d_in[0];
    const int*   batch = (const int*)d_in[1];
    const int*   e0 = (const int*)d_in[2];
    const int*   e1 = (const int*)d_in[3];
    const int*   e2 = (const int*)d_in[4];
    const int*   e3 = (const int*)d_in[5];
    const int*   e4 = (const int*)d_in[6];
    const float* W0    = (const float*)d_in[7];
    const float* root0 = (const float*)d_in[8];
    const float* b0    = (const float*)d_in[9];
    const float* Wl    = (const float*)d_in[10];
    const float* rootl = (const float*)d_in[11];
    const float* bl    = (const float*)d_in[12];
    const float* Wc1   = (const float*)d_in[13];
    const float* bc1   = (const float*)d_in[14];
    const float* Wc2   = (const float*)d_in[15];
    const float* bc2   = (const float*)d_in[16];
    const float* Wc3   = (const float*)d_in[17];
    const float* bc3   = (const float*)d_in[18];
    const int E = in_sizes[2] / 2;

    // ---- workspace carve-up (256-B aligned) ----
    char* base = (char*)d_ws;
    size_t o = 0;
    auto carve = [&](size_t bytes) -> char* {
        char* p = base + o;
        o = (o + bytes + 255) & ~(size_t)255;
        return p;
    };
    unsigned short* Y    = (unsigned short*)carve((size_t)6 * NPAD * HID * 2);
    unsigned short* hA   = (unsigned short*)carve((size_t)NPAD * HID * 2);
    unsigned short* hB   = (unsigned short*)carve((size_t)NPAD * HID * 2);
    int*   cnt  = (int*)carve((size_t)M5 * 4);
    int*   offs = (int*)carve((size_t)M5 * 4);
    int*   cur  = (int*)carve((size_t)M5 * 4);
    float* invc = (float*)carve((size_t)M5 * 4);
    int*   csr  = (int*)carve((size_t)R_REL * E * 4);
    int*   bsum = (int*)carve(2048);
    float* pooled = (float*)carve((size_t)G_GRAPHS * HID * 4);
    short* Wt0  = (short*)carve((size_t)6 * 128 * KPAD0 * 2);
    short* Wtl  = (short*)carve((size_t)L_LAYERS * 6 * 128 * HID * 2);

    // ---- CSR build ----
    hipMemsetAsync(cnt, 0, (size_t)M5 * 4, stream);
    hipMemsetAsync(pooled, 0, (size_t)G_GRAPHS * HID * 4, stream);
    int eg = (R_REL * E + 255) / 256;
    k_count<<<eg, 256, 0, stream>>>(e0, e1, e2, e3, e4, cnt, E);
    int nblk = (M5 + 1023) / 1024;   // 489
    k_scan1<<<nblk, 256, 0, stream>>>(cnt, offs, bsum);
    k_scan2<<<1, 512, 0, stream>>>(bsum, nblk);
    k_scan3<<<(M5 + 255) / 256, 256, 0, stream>>>(offs, bsum, cur, cnt, invc);
    k_fill<<<eg, 256, 0, stream>>>(e0, e1, e2, e3, e4, cur, csr, E);

    // ---- weight transpose+cast ----
    k_tw0<<<(6 * 128 * KPAD0 + 255) / 256, 256, 0, stream>>>(root0, W0, Wt0);
    k_twl<<<(L_LAYERS * 6 * 128 * HID + 255) / 256, 256, 0, stream>>>(rootl, Wl, Wtl);

    dim3 ggrid(NPAD / 128, 6);
    int agg_grid = N_NODES * HID / 256;   // 50000

    // ---- layer 0 ----
    gemm_mfma<KPAD0, true><<<ggrid, 256, 0, stream>>>(X, Wt0, Y, N_NODES, IN_F);
    aggregate<<<agg_grid, 256, 0, stream>>>(Y, csr, offs, cnt, invc, b0, hA);

    // ---- layers 1..2 ----
    unsigned short* hin = hA; unsigned short* hout = hB;
    for (int l = 0; l < L_LAYERS; l++) {
        gemm_mfma<HID, false><<<ggrid, 256, 0, stream>>>(hin, Wtl + (size_t)l * 6 * 128 * HID,
                                                         Y, N_NODES, HID);
        aggregate<<<agg_grid, 256, 0, stream>>>(Y, csr, offs, cnt, invc, bl + (size_t)l * HID, hout);
        unsigned short* t = hin; hin = hout; hout = t;
    }

    // ---- readout ----
    k_pool<<<(N_NODES + 127) / 128, 128, 0, stream>>>(hin, batch, pooled);
    k_mlp<<<G_GRAPHS, 128, 0, stream>>>(pooled, batch, Wc1, bc1, Wc2, bc2, Wc3, bc3, (float*)d_out);
}

// Round 3
// 718.798 us; speedup vs baseline: 3.0873x; 1.4921x over previous
//
#include <hip/hip_runtime.h>

#define N_NODES 100000
#define NPAD    100096      // 782 * 128
#define G_GRAPHS 256
#define IN_F 162
#define KPAD0 192
#define HID 128
#define R_REL 5
#define L_LAYERS 2
#define M5 (R_REL * N_NODES)

typedef __attribute__((ext_vector_type(8))) short bf16x8;
typedef __attribute__((ext_vector_type(4))) float f32x4;

__device__ __forceinline__ short f2bf(float f) {
    union { float f; unsigned u; } v; v.f = f;
    unsigned r = (v.u + 0x7fffu + ((v.u >> 16) & 1u)) >> 16;
    return (short)r;
}
__device__ __forceinline__ float bf2f(unsigned short u) {
    union { unsigned u; float f; } v; v.u = ((unsigned)u) << 16;
    return v.f;
}

// ---------------- CSR build (merged across relations, dst-major) ----------------
__global__ void k_count(const int* e0, const int* e1, const int* e2,
                        const int* e3, const int* e4, int* cnt, int E) {
    int gid = blockIdx.x * 256 + threadIdx.x;
    if (gid >= R_REL * E) return;
    int r = gid / E, e = gid - r * E;
    const int* ei = (r == 0) ? e0 : (r == 1) ? e1 : (r == 2) ? e2 : (r == 3) ? e3 : e4;
    atomicAdd(&cnt[r * N_NODES + ei[E + e]], 1);
}

// block scans 1024 node-totals (256 thr x 4); value[d] = sum_r cnt[r][d]
__global__ __launch_bounds__(256) void k_scan1(const int* __restrict__ cnt,
                                               int* __restrict__ off, int* __restrict__ bsum) {
    __shared__ int ts[256];
    int t = threadIdx.x;
    int base = blockIdx.x * 1024 + t * 4;
    int v[4];
    #pragma unroll
    for (int j = 0; j < 4; j++) {
        int d = base + j;
        int s = 0;
        if (d < N_NODES) {
            #pragma unroll
            for (int r = 0; r < R_REL; r++) s += cnt[r * N_NODES + d];
        }
        v[j] = s;
    }
    int tsum = v[0] + v[1] + v[2] + v[3];
    ts[t] = tsum; __syncthreads();
    for (int o = 1; o < 256; o <<= 1) {
        int x = (t >= o) ? ts[t - o] : 0;
        __syncthreads();
        ts[t] += x;
        __syncthreads();
    }
    if (t == 255) bsum[blockIdx.x] = ts[255];
    int run = ts[t] - tsum;
    #pragma unroll
    for (int j = 0; j < 4; j++) { if (base + j < N_NODES) off[base + j] = run; run += v[j]; }
}

__global__ __launch_bounds__(512) void k_scan2(int* bsum, int nblk) {
    __shared__ int ts[512];
    int t = threadIdx.x;
    int v = (t < nblk) ? bsum[t] : 0;
    ts[t] = v; __syncthreads();
    for (int o = 1; o < 512; o <<= 1) {
        int x = (t >= o) ? ts[t - o] : 0;
        __syncthreads();
        ts[t] += x;
        __syncthreads();
    }
    if (t < nblk) bsum[t] = ts[t] - v;   // exclusive
}

__global__ void k_scan3(const int* __restrict__ off, const int* __restrict__ bsum,
                        int* __restrict__ mstart, int* __restrict__ mcur,
                        const int* __restrict__ cnt, float* __restrict__ invc) {
    int i = blockIdx.x * 256 + threadIdx.x;
    if (i >= N_NODES) return;
    int o = off[i] + bsum[i >> 10];
    mstart[i] = o;
    mcur[i] = o;
    int tc = 0;
    #pragma unroll
    for (int r = 0; r < R_REL; r++) {
        int c = cnt[r * N_NODES + i];
        tc += c;
        invc[r * N_NODES + i] = 1.0f / (float)max(c, 1);
    }
    if (i == N_NODES - 1) mstart[N_NODES] = o + tc;
}

// mrec = absolute ushort-offset of source row in Y; mw = 1/deg(dst, r)
__global__ void k_fill(const int* e0, const int* e1, const int* e2,
                       const int* e3, const int* e4, int* mcur,
                       const float* __restrict__ invc,
                       int* __restrict__ mrec, float* __restrict__ mw, int E) {
    int gid = blockIdx.x * 256 + threadIdx.x;
    if (gid >= R_REL * E) return;
    int r = gid / E, e = gid - r * E;
    const int* ei = (r == 0) ? e0 : (r == 1) ? e1 : (r == 2) ? e2 : (r == 3) ? e3 : e4;
    int src = ei[e], dst = ei[E + e];
    int pos = atomicAdd(&mcur[dst], 1);
    mrec[pos] = ((1 + r) * NPAD + src) * HID;
    mw[pos] = invc[r * N_NODES + dst];
}

// ---------------- weight pre-transpose (fp32 -> bf16, [chunk][col][Kpad]) ----------------
__global__ void k_tw0(const float* __restrict__ root0, const float* __restrict__ W0,
                      short* __restrict__ out) {
    int gid = blockIdx.x * 256 + threadIdx.x;   // 6*128*192
    if (gid >= 6 * 128 * KPAD0) return;
    int chunk = gid / (128 * KPAD0);
    int rem = gid - chunk * 128 * KPAD0;
    int col = rem / KPAD0;
    int k = rem - col * KPAD0;
    float v = 0.f;
    if (k < IN_F)
        v = (chunk == 0) ? root0[k * HID + col]
                         : W0[((size_t)(chunk - 1) * IN_F + k) * HID + col];
    out[gid] = f2bf(v);
}

__global__ void k_twl(const float* __restrict__ rootl, const float* __restrict__ Wl,
                      short* __restrict__ out) {
    int gid = blockIdx.x * 256 + threadIdx.x;   // 2*6*128*128
    if (gid >= L_LAYERS * 6 * 128 * HID) return;
    int l = gid / (6 * 128 * HID);
    int rem = gid - l * 6 * 128 * HID;
    int chunk = rem / (128 * HID);
    int rem2 = rem - chunk * 128 * HID;
    int col = rem2 / HID;
    int k = rem2 - col * HID;
    float v = (chunk == 0) ? rootl[((size_t)l * HID + k) * HID + col]
                           : Wl[(((size_t)l * R_REL + (chunk - 1)) * HID + k) * HID + col];
    out[gid] = f2bf(v);
}

// ---------------- MFMA GEMM, A staged once, 6 chunks per block ----------------
// 128 rows x full K in LDS; per chunk: stage B(128x K), MFMA, LDS epilogue, 16B stores.
template<int KP, bool A_F32>
__global__ __launch_bounds__(256, 2)
void gemm_fused(const void* __restrict__ Av, const short* __restrict__ Wt,
                unsigned short* __restrict__ Y, int M, int Kreal) {
    constexpr int SA = KP + 8;        // LDS row stride in shorts
    constexpr int NC8 = KP / 8;
    __shared__ short As[128 * SA];
    __shared__ short Bs[128 * SA];
    const int tid = threadIdx.x;
    const int row0 = blockIdx.x * 128;
    const int lane = tid & 63, wv = tid >> 6;
    const int quad = lane >> 4, l16 = lane & 15;
    const int wr0 = (wv >> 1) * 64, wc0 = (wv & 1) * 64;

    // ---- stage A (full K) once ----
    for (int cidx = tid; cidx < 128 * NC8; cidx += 256) {
        int row = cidx / NC8, c8 = cidx - row * NC8;
        int grow = row0 + row, k = c8 * 8;
        bf16x8 v = (bf16x8){0,0,0,0,0,0,0,0};
        if (grow < M) {
            if (A_F32) {
                const float* Af = (const float*)Av;
                #pragma unroll
                for (int j = 0; j < 8; j++) {
                    int kk = k + j;
                    float f = (kk < Kreal) ? Af[(size_t)grow * Kreal + kk] : 0.f;
                    v[j] = f2bf(f);
                }
            } else {
                v = *(const bf16x8*)((const short*)Av + (size_t)grow * KP + k);
            }
        }
        *(bf16x8*)&As[row * SA + k] = v;
    }

    for (int chunk = 0; chunk < 6; chunk++) {
        __syncthreads();   // prev epilogue readers done / A staged (iter 0)
        const short* Wc = Wt + (size_t)chunk * 128 * KP;
        for (int cidx = tid; cidx < 128 * NC8; cidx += 256) {
            int row = cidx / NC8, c8 = cidx - row * NC8;
            *(bf16x8*)&Bs[row * SA + c8 * 8] = *(const bf16x8*)&Wc[row * KP + c8 * 8];
        }
        __syncthreads();

        f32x4 acc[4][4];
        #pragma unroll
        for (int i = 0; i < 4; i++)
            #pragma unroll
            for (int j = 0; j < 4; j++) acc[i][j] = (f32x4){0.f, 0.f, 0.f, 0.f};

        #pragma unroll
        for (int ks = 0; ks < KP / 32; ks++) {
            int k0 = ks * 32;
            bf16x8 af[4], bfr[4];
            #pragma unroll
            for (int i = 0; i < 4; i++)
                af[i] = *(const bf16x8*)&As[(wr0 + i * 16 + l16) * SA + k0 + quad * 8];
            #pragma unroll
            for (int j = 0; j < 4; j++)
                bfr[j] = *(const bf16x8*)&Bs[(wc0 + j * 16 + l16) * SA + k0 + quad * 8];
            #pragma unroll
            for (int i = 0; i < 4; i++)
                #pragma unroll
                for (int j = 0; j < 4; j++)
                    acc[i][j] = __builtin_amdgcn_mfma_f32_16x16x32_bf16(af[i], bfr[j], acc[i][j], 0, 0, 0);
        }
        __syncthreads();   // waves done reading Bs

        // epilogue: acc -> Bs (bf16), then full-line coalesced stores
        #pragma unroll
        for (int i = 0; i < 4; i++)
            #pragma unroll
            for (int j = 0; j < 4; j++)
                #pragma unroll
                for (int reg = 0; reg < 4; reg++)
                    Bs[(wr0 + i * 16 + quad * 4 + reg) * SA + wc0 + j * 16 + l16] =
                        f2bf(acc[i][j][reg]);
        __syncthreads();

        unsigned short* Yc = Y + (size_t)chunk * NPAD * HID + (size_t)row0 * HID;
        #pragma unroll
        for (int s = 0; s < 8; s++) {
            int row = (tid >> 4) + s * 16;
            int col = (tid & 15) * 8;
            bf16x8 v = *(const bf16x8*)&Bs[row * SA + col];
            *(bf16x8*)&Yc[(size_t)row * HID + col] = v;
        }
    }
}

// ---------------- aggregation: one wave per dst node ----------------
// acc = bias + root(Y chunk0) + sum_e w[e] * Y[rec[e]]; relu -> bf16
__global__ __launch_bounds__(256)
void aggregate(const unsigned short* __restrict__ Yall, const int* __restrict__ mstart,
               const int* __restrict__ mrec, const float* __restrict__ mw,
               const float* __restrict__ bias, unsigned short* __restrict__ hout) {
    int wid = (blockIdx.x * 256 + threadIdx.x) >> 6;
    int lane = threadIdx.x & 63;
    if (wid >= N_NODES) return;
    int d = wid;
    int s = mstart[d], e = mstart[d + 1];

    float2 b2 = *(const float2*)&bias[lane * 2];
    unsigned rv = *(const unsigned*)&Yall[(size_t)d * HID + lane * 2];
    float s0 = b2.x + bf2f((unsigned short)(rv & 0xffff));
    float s1 = b2.y + bf2f((unsigned short)(rv >> 16));

    for (int base = s; base < e; base += 64) {
        int m = e - base;
        int rec = 0; float w = 0.f;
        if (lane < m) { rec = mrec[base + lane]; w = mw[base + lane]; }
        int cnt = min(m, 64);
        for (int j = 0; j < cnt; j++) {
            int off = __shfl(rec, j, 64);
            float wj = __shfl(w, j, 64);
            unsigned v = *(const unsigned*)&Yall[(size_t)off + lane * 2];
            s0 += wj * bf2f((unsigned short)(v & 0xffff));
            s1 += wj * bf2f((unsigned short)(v >> 16));
        }
    }
    unsigned lo = (unsigned short)f2bf(fmaxf(s0, 0.f));
    unsigned hi = (unsigned short)f2bf(fmaxf(s1, 0.f));
    *(unsigned*)&hout[(size_t)d * HID + lane * 2] = lo | (hi << 16);
}

// ---------------- readout: parallel pooling + per-graph MLP ----------------
__global__ __launch_bounds__(128)
void k_pool(const unsigned short* __restrict__ h, const int* __restrict__ batch,
            float* __restrict__ pooled) {
    int c = threadIdx.x;
    int start = blockIdx.x * 128;
    if (start >= N_NODES) return;
    int end = min(start + 128, N_NODES);
    int g = batch[start];
    float s = 0.f;
    for (int i = start; i < end; i++) {
        int gi = batch[i];
        if (gi != g) { atomicAdd(&pooled[g * HID + c], s); s = 0.f; g = gi; }
        s += bf2f(h[(size_t)i * HID + c]);
    }
    atomicAdd(&pooled[g * HID + c], s);
}

__device__ int lower_bound_i(const int* a, int n, int v) {
    int lo = 0, hi = n;
    while (lo < hi) {
        int mid = (lo + hi) >> 1;
        if (a[mid] < v) lo = mid + 1; else hi = mid;
    }
    return lo;
}

__global__ __launch_bounds__(128)
void k_mlp(const float* __restrict__ pooled, const int* __restrict__ batch,
           const float* __restrict__ Wc1, const float* __restrict__ bc1,
           const float* __restrict__ Wc2, const float* __restrict__ bc2,
           const float* __restrict__ Wc3, const float* __restrict__ bc3,
           float* __restrict__ out) {
    int g = blockIdx.x;
    int c = threadIdx.x;
    __shared__ int range[2];
    if (c == 0) range[0] = lower_bound_i(batch, N_NODES, g);
    if (c == 1) range[1] = lower_bound_i(batch, N_NODES, g + 1);
    __syncthreads();
    float denom = fmaxf((float)(range[1] - range[0]), 1.0f);
    __shared__ float row[HID], h1[HID], h2[HID];
    row[c] = pooled[g * HID + c] / denom;
    __syncthreads();
    float acc = bc1[c];
    for (int k = 0; k < HID; k++) acc += row[k] * Wc1[k * HID + c];
    h1[c] = fmaxf(acc, 0.f);
    __syncthreads();
    acc = bc2[c];
    for (int k = 0; k < HID; k++) acc += h1[k] * Wc2[k * HID + c];
    h2[c] = fmaxf(acc, 0.f);
    __syncthreads();
    float t = h2[c] * Wc3[c];
    for (int off = 32; off > 0; off >>= 1) t += __shfl_down(t, off, 64);
    __shared__ float part[2];
    if ((c & 63) == 0) part[c >> 6] = t;
    __syncthreads();
    if (c == 0) out[g] = part[0] + part[1] + bc3[0];
}

// ---------------- launcher ----------------
extern "C" void kernel_launch(void* const* d_in, const int* in_sizes, int n_in,
                              void* d_out, int out_size, void* d_ws, size_t ws_size,
                              hipStream_t stream) {
    const float* X     = (const float*)d_in[0];
    const int*   batch = (const int*)d_in[1];
    const int*   e0 = (const int*)d_in[2];
    const int*   e1 = (const int*)d_in[3];
    const int*   e2 = (const int*)d_in[4];
    const int*   e3 = (const int*)d_in[5];
    const int*   e4 = (const int*)d_in[6];
    const float* W0    = (const float*)d_in[7];
    const float* root0 = (const float*)d_in[8];
    const float* b0    = (const float*)d_in[9];
    const float* Wl    = (const float*)d_in[10];
    const float* rootl = (const float*)d_in[11];
    const float* bl    = (const float*)d_in[12];
    const float* Wc1   = (const float*)d_in[13];
    const float* bc1   = (const float*)d_in[14];
    const float* Wc2   = (const float*)d_in[15];
    const float* bc2   = (const float*)d_in[16];
    const float* Wc3   = (const float*)d_in[17];
    const float* bc3   = (const float*)d_in[18];
    const int E = in_sizes[2] / 2;
    const int NE = R_REL * E;

    char* base = (char*)d_ws;
    size_t o = 0;
    auto carve = [&](size_t bytes) -> char* {
        char* p = base + o;
        o = (o + bytes + 255) & ~(size_t)255;
        return p;
    };
    unsigned short* Y    = (unsigned short*)carve((size_t)6 * NPAD * HID * 2);
    unsigned short* hA   = (unsigned short*)carve((size_t)NPAD * HID * 2);
    unsigned short* hB   = (unsigned short*)carve((size_t)NPAD * HID * 2);
    int*   cnt    = (int*)carve((size_t)M5 * 4);
    float* invc   = (float*)carve((size_t)M5 * 4);
    int*   offsc  = (int*)carve((size_t)N_NODES * 4);
    int*   mstart = (int*)carve((size_t)(N_NODES + 1) * 4);
    int*   mcur   = (int*)carve((size_t)N_NODES * 4);
    int*   mrec   = (int*)carve((size_t)NE * 4);
    float* mw     = (float*)carve((size_t)NE * 4);
    int*   bsum   = (int*)carve(2048);
    float* pooled = (float*)carve((size_t)G_GRAPHS * HID * 4);
    short* Wt0    = (short*)carve((size_t)6 * 128 * KPAD0 * 2);
    short* Wtl    = (short*)carve((size_t)L_LAYERS * 6 * 128 * HID * 2);

    // ---- CSR build ----
    hipMemsetAsync(cnt, 0, (size_t)M5 * 4, stream);
    hipMemsetAsync(pooled, 0, (size_t)G_GRAPHS * HID * 4, stream);
    int eg = (NE + 255) / 256;
    k_count<<<eg, 256, 0, stream>>>(e0, e1, e2, e3, e4, cnt, E);
    int nblk = (N_NODES + 1023) / 1024;   // 98
    k_scan1<<<nblk, 256, 0, stream>>>(cnt, offsc, bsum);
    k_scan2<<<1, 512, 0, stream>>>(bsum, nblk);
    k_scan3<<<(N_NODES + 255) / 256, 256, 0, stream>>>(offsc, bsum, mstart, mcur, cnt, invc);
    k_fill<<<eg, 256, 0, stream>>>(e0, e1, e2, e3, e4, mcur, invc, mrec, mw, E);

    // ---- weight transpose+cast ----
    k_tw0<<<(6 * 128 * KPAD0 + 255) / 256, 256, 0, stream>>>(root0, W0, Wt0);
    k_twl<<<(L_LAYERS * 6 * 128 * HID + 255) / 256, 256, 0, stream>>>(rootl, Wl, Wtl);

    int ggrid = NPAD / 128;               // 782
    int agg_grid = (N_NODES + 3) / 4;     // one wave per node, 4 waves/block

    // ---- layer 0 ----
    gemm_fused<KPAD0, true><<<ggrid, 256, 0, stream>>>(X, Wt0, Y, N_NODES, IN_F);
    aggregate<<<agg_grid, 256, 0, stream>>>(Y, mstart, mrec, mw, b0, hA);

    // ---- layers 1..2 ----
    unsigned short* hin = hA; unsigned short* hout = hB;
    for (int l = 0; l < L_LAYERS; l++) {
        gemm_fused<HID, false><<<ggrid, 256, 0, stream>>>(hin, Wtl + (size_t)l * 6 * 128 * HID,
                                                          Y, N_NODES, HID);
        aggregate<<<agg_grid, 256, 0, stream>>>(Y, mstart, mrec, mw, bl + (size_t)l * HID, hout);
        unsigned short* t = hin; hin = hout; hout = t;
    }

    // ---- readout ----
    k_pool<<<(N_NODES + 127) / 128, 128, 0, stream>>>(hin, batch, pooled);
    k_mlp<<<G_GRAPHS, 128, 0, stream>>>(pooled, batch, Wc1, bc1, Wc2, bc2, Wc3, bc3, (float*)d_out);
}

// Round 4
// 693.301 us; speedup vs baseline: 3.2008x; 1.0368x over previous
//
#include <hip/hip_runtime.h>

#define N_NODES 100000
#define NPAD    100096      // 782 * 128
#define NTILES  782
#define TPX     98          // row-tiles per XCD (8*98 = 784 >= 782)
#define G_GRAPHS 256
#define IN_F 162
#define KPAD0 192
#define HID 128
#define R_REL 5
#define L_LAYERS 2
#define M5 (R_REL * N_NODES)

typedef __attribute__((ext_vector_type(8))) short bf16x8;
typedef __attribute__((ext_vector_type(4))) float f32x4;

__device__ __forceinline__ short f2bf(float f) {
    union { float f; unsigned u; } v; v.f = f;
    unsigned r = (v.u + 0x7fffu + ((v.u >> 16) & 1u)) >> 16;
    return (short)r;
}
__device__ __forceinline__ float bf2f(unsigned short u) {
    union { unsigned u; float f; } v; v.u = ((unsigned)u) << 16;
    return v.f;
}

// ---------------- CSR build (merged across relations, dst-major) ----------------
__global__ void k_count(const int* e0, const int* e1, const int* e2,
                        const int* e3, const int* e4, int* cnt, int E) {
    int gid = blockIdx.x * 256 + threadIdx.x;
    if (gid >= R_REL * E) return;
    int r = gid / E, e = gid - r * E;
    const int* ei = (r == 0) ? e0 : (r == 1) ? e1 : (r == 2) ? e2 : (r == 3) ? e3 : e4;
    atomicAdd(&cnt[r * N_NODES + ei[E + e]], 1);
}

__global__ __launch_bounds__(256) void k_scan1(const int* __restrict__ cnt,
                                               int* __restrict__ off, int* __restrict__ bsum) {
    __shared__ int ts[256];
    int t = threadIdx.x;
    int base = blockIdx.x * 1024 + t * 4;
    int v[4];
    #pragma unroll
    for (int j = 0; j < 4; j++) {
        int d = base + j;
        int s = 0;
        if (d < N_NODES) {
            #pragma unroll
            for (int r = 0; r < R_REL; r++) s += cnt[r * N_NODES + d];
        }
        v[j] = s;
    }
    int tsum = v[0] + v[1] + v[2] + v[3];
    ts[t] = tsum; __syncthreads();
    for (int o = 1; o < 256; o <<= 1) {
        int x = (t >= o) ? ts[t - o] : 0;
        __syncthreads();
        ts[t] += x;
        __syncthreads();
    }
    if (t == 255) bsum[blockIdx.x] = ts[255];
    int run = ts[t] - tsum;
    #pragma unroll
    for (int j = 0; j < 4; j++) { if (base + j < N_NODES) off[base + j] = run; run += v[j]; }
}

__global__ __launch_bounds__(512) void k_scan2(int* bsum, int nblk) {
    __shared__ int ts[512];
    int t = threadIdx.x;
    int v = (t < nblk) ? bsum[t] : 0;
    ts[t] = v; __syncthreads();
    for (int o = 1; o < 512; o <<= 1) {
        int x = (t >= o) ? ts[t - o] : 0;
        __syncthreads();
        ts[t] += x;
        __syncthreads();
    }
    if (t < nblk) bsum[t] = ts[t] - v;   // exclusive
}

__global__ void k_scan3(const int* __restrict__ off, const int* __restrict__ bsum,
                        int* __restrict__ mstart, int* __restrict__ mcur,
                        const int* __restrict__ cnt, float* __restrict__ invc) {
    int i = blockIdx.x * 256 + threadIdx.x;
    if (i >= N_NODES) return;
    int o = off[i] + bsum[i >> 10];
    mstart[i] = o;
    mcur[i] = o;
    int tc = 0;
    #pragma unroll
    for (int r = 0; r < R_REL; r++) {
        int c = cnt[r * N_NODES + i];
        tc += c;
        invc[r * N_NODES + i] = 1.0f / (float)max(c, 1);
    }
    if (i == N_NODES - 1) mstart[N_NODES] = o + tc;
}

__global__ void k_fill(const int* e0, const int* e1, const int* e2,
                       const int* e3, const int* e4, int* mcur,
                       const float* __restrict__ invc,
                       int* __restrict__ mrec, float* __restrict__ mw, int E) {
    int gid = blockIdx.x * 256 + threadIdx.x;
    if (gid >= R_REL * E) return;
    int r = gid / E, e = gid - r * E;
    const int* ei = (r == 0) ? e0 : (r == 1) ? e1 : (r == 2) ? e2 : (r == 3) ? e3 : e4;
    int src = ei[e], dst = ei[E + e];
    int pos = atomicAdd(&mcur[dst], 1);
    mrec[pos] = ((1 + r) * NPAD + src) * HID;
    mw[pos] = invc[r * N_NODES + dst];
}

// ---------------- X fp32 -> bf16, padded [NPAD][192] ----------------
__global__ void k_castX(const float* __restrict__ X, unsigned short* __restrict__ Xb) {
    int gid = blockIdx.x * 256 + threadIdx.x;
    if (gid >= NPAD * KPAD0) return;
    int row = gid / KPAD0, k = gid - row * KPAD0;
    float v = (row < N_NODES && k < IN_F) ? X[(size_t)row * IN_F + k] : 0.f;
    Xb[gid] = (unsigned short)f2bf(v);
}

// ---------------- weight pre-transpose (fp32 -> bf16, [chunk][col][Kpad]) ----------------
__global__ void k_tw0(const float* __restrict__ root0, const float* __restrict__ W0,
                      short* __restrict__ out) {
    int gid = blockIdx.x * 256 + threadIdx.x;   // 6*128*192
    if (gid >= 6 * 128 * KPAD0) return;
    int chunk = gid / (128 * KPAD0);
    int rem = gid - chunk * 128 * KPAD0;
    int col = rem / KPAD0;
    int k = rem - col * KPAD0;
    float v = 0.f;
    if (k < IN_F)
        v = (chunk == 0) ? root0[k * HID + col]
                         : W0[((size_t)(chunk - 1) * IN_F + k) * HID + col];
    out[gid] = f2bf(v);
}

__global__ void k_twl(const float* __restrict__ rootl, const float* __restrict__ Wl,
                      short* __restrict__ out) {
    int gid = blockIdx.x * 256 + threadIdx.x;   // 2*6*128*128
    if (gid >= L_LAYERS * 6 * 128 * HID) return;
    int l = gid / (6 * 128 * HID);
    int rem = gid - l * 6 * 128 * HID;
    int chunk = rem / (128 * HID);
    int rem2 = rem - chunk * 128 * HID;
    int col = rem2 / HID;
    int k = rem2 - col * HID;
    float v = (chunk == 0) ? rootl[((size_t)l * HID + k) * HID + col]
                           : Wl[(((size_t)l * R_REL + (chunk - 1)) * HID + k) * HID + col];
    out[gid] = f2bf(v);
}

// ---------------- MFMA GEMM: B in LDS once, A direct-to-fragment, XCD swizzle ----------------
// Y[chunk][row][128] = A[row][KP] @ Wt[chunk][col][KP]^T, 128x128 tile per block.
template<int KP>
__global__ __launch_bounds__(256)
void gemm_direct(const unsigned short* __restrict__ A, const short* __restrict__ Wt,
                 unsigned short* __restrict__ Y) {
    constexpr int KS = KP / 32;                 // 4 or 6
    constexpr int PF = (KS > 4) ? 2 : KS;       // A-prefetch batch
    constexpr int SA = KP + 8;                  // LDS row stride (shorts)
    __shared__ short Bs[128 * SA];

    // XCD-aware mapping: XCD (bid&7) owns row-tiles [xcd*98, xcd*98+98) x all 6 chunks
    int bid = blockIdx.x;
    int xcd = bid & 7, slot = bid >> 3;         // slot in [0, 588)
    int chunk = slot / TPX;
    int rt = xcd * TPX + (slot - chunk * TPX);
    if (rt >= NTILES) return;
    const int row0 = rt * 128;

    const int tid = threadIdx.x;
    const int lane = tid & 63, wv = tid >> 6;
    const int quad = lane >> 4, l16 = lane & 15;
    const int wr0 = (wv >> 1) * 64, wc0 = (wv & 1) * 64;

    const size_t arow = (size_t)(row0 + wr0 + l16) * KP + quad * 8;

    // prefetch first A batch (global, independent of LDS)
    bf16x8 cur[PF][4], nxt[PF][4];
    #pragma unroll
    for (int p = 0; p < PF; p++)
        #pragma unroll
        for (int i = 0; i < 4; i++)
            cur[p][i] = *(const bf16x8*)&A[arow + (size_t)i * 16 * KP + p * 32];

    // stage B (one chunk of weights) once
    const short* Wc = Wt + (size_t)chunk * 128 * KP;
    for (int cidx = tid; cidx < 128 * (KP / 8); cidx += 256) {
        int row = cidx / (KP / 8), c8 = cidx - row * (KP / 8);
        *(bf16x8*)&Bs[row * SA + c8 * 8] = *(const bf16x8*)&Wc[row * KP + c8 * 8];
    }
    __syncthreads();

    f32x4 acc[4][4];
    #pragma unroll
    for (int i = 0; i < 4; i++)
        #pragma unroll
        for (int j = 0; j < 4; j++) acc[i][j] = (f32x4){0.f, 0.f, 0.f, 0.f};

    for (int kb = 0; kb < KS; kb += PF) {
        if (kb + PF < KS) {
            #pragma unroll
            for (int p = 0; p < PF; p++)
                #pragma unroll
                for (int i = 0; i < 4; i++)
                    nxt[p][i] = *(const bf16x8*)&A[arow + (size_t)i * 16 * KP + (kb + PF + p) * 32];
        }
        #pragma unroll
        for (int p = 0; p < PF; p++) {
            int k0 = (kb + p) * 32;
            bf16x8 bfr[4];
            #pragma unroll
            for (int j = 0; j < 4; j++)
                bfr[j] = *(const bf16x8*)&Bs[(wc0 + j * 16 + l16) * SA + k0 + quad * 8];
            #pragma unroll
            for (int i = 0; i < 4; i++)
                #pragma unroll
                for (int j = 0; j < 4; j++)
                    acc[i][j] = __builtin_amdgcn_mfma_f32_16x16x32_bf16(cur[p][i], bfr[j], acc[i][j], 0, 0, 0);
        }
        #pragma unroll
        for (int p = 0; p < PF; p++)
            #pragma unroll
            for (int i = 0; i < 4; i++)
                cur[p][i] = nxt[p][i];
    }
    __syncthreads();   // all waves done reading Bs

    // epilogue: acc -> Bs (bf16), then full-line coalesced stores
    #pragma unroll
    for (int i = 0; i < 4; i++)
        #pragma unroll
        for (int j = 0; j < 4; j++)
            #pragma unroll
            for (int reg = 0; reg < 4; reg++)
                Bs[(wr0 + i * 16 + quad * 4 + reg) * SA + wc0 + j * 16 + l16] =
                    f2bf(acc[i][j][reg]);
    __syncthreads();

    unsigned short* Yc = Y + (size_t)chunk * NPAD * HID + (size_t)row0 * HID;
    #pragma unroll
    for (int s = 0; s < 8; s++) {
        int row = (tid >> 4) + s * 16;
        int col = (tid & 15) * 8;
        bf16x8 v = *(const bf16x8*)&Bs[row * SA + col];
        *(bf16x8*)&Yc[(size_t)row * HID + col] = v;
    }
}

// ---------------- aggregation: one wave per dst node ----------------
__global__ __launch_bounds__(256)
void aggregate(const unsigned short* __restrict__ Yall, const int* __restrict__ mstart,
               const int* __restrict__ mrec, const float* __restrict__ mw,
               const float* __restrict__ bias, unsigned short* __restrict__ hout) {
    int wid = (blockIdx.x * 256 + threadIdx.x) >> 6;
    int lane = threadIdx.x & 63;
    if (wid >= N_NODES) return;
    int d = wid;
    int s = mstart[d], e = mstart[d + 1];

    float2 b2 = *(const float2*)&bias[lane * 2];
    unsigned rv = *(const unsigned*)&Yall[(size_t)d * HID + lane * 2];
    float s0 = b2.x + bf2f((unsigned short)(rv & 0xffff));
    float s1 = b2.y + bf2f((unsigned short)(rv >> 16));

    for (int base = s; base < e; base += 64) {
        int m = e - base;
        int rec = 0; float w = 0.f;
        if (lane < m) { rec = mrec[base + lane]; w = mw[base + lane]; }
        int cnt = min(m, 64);
        for (int j = 0; j < cnt; j++) {
            int off = __shfl(rec, j, 64);
            float wj = __shfl(w, j, 64);
            unsigned v = *(const unsigned*)&Yall[(size_t)off + lane * 2];
            s0 += wj * bf2f((unsigned short)(v & 0xffff));
            s1 += wj * bf2f((unsigned short)(v >> 16));
        }
    }
    unsigned lo = (unsigned short)f2bf(fmaxf(s0, 0.f));
    unsigned hi = (unsigned short)f2bf(fmaxf(s1, 0.f));
    *(unsigned*)&hout[(size_t)d * HID + lane * 2] = lo | (hi << 16);
}

// ---------------- readout ----------------
__global__ __launch_bounds__(128)
void k_pool(const unsigned short* __restrict__ h, const int* __restrict__ batch,
            float* __restrict__ pooled) {
    int c = threadIdx.x;
    int start = blockIdx.x * 128;
    if (start >= N_NODES) return;
    int end = min(start + 128, N_NODES);
    int g = batch[start];
    float s = 0.f;
    for (int i = start; i < end; i++) {
        int gi = batch[i];
        if (gi != g) { atomicAdd(&pooled[g * HID + c], s); s = 0.f; g = gi; }
        s += bf2f(h[(size_t)i * HID + c]);
    }
    atomicAdd(&pooled[g * HID + c], s);
}

__device__ int lower_bound_i(const int* a, int n, int v) {
    int lo = 0, hi = n;
    while (lo < hi) {
        int mid = (lo + hi) >> 1;
        if (a[mid] < v) lo = mid + 1; else hi = mid;
    }
    return lo;
}

__global__ __launch_bounds__(128)
void k_mlp(const float* __restrict__ pooled, const int* __restrict__ batch,
           const float* __restrict__ Wc1, const float* __restrict__ bc1,
           const float* __restrict__ Wc2, const float* __restrict__ bc2,
           const float* __restrict__ Wc3, const float* __restrict__ bc3,
           float* __restrict__ out) {
    int g = blockIdx.x;
    int c = threadIdx.x;
    __shared__ int range[2];
    if (c == 0) range[0] = lower_bound_i(batch, N_NODES, g);
    if (c == 1) range[1] = lower_bound_i(batch, N_NODES, g + 1);
    __syncthreads();
    float denom = fmaxf((float)(range[1] - range[0]), 1.0f);
    __shared__ float row[HID], h1[HID], h2[HID];
    row[c] = pooled[g * HID + c] / denom;
    __syncthreads();
    float acc = bc1[c];
    for (int k = 0; k < HID; k++) acc += row[k] * Wc1[k * HID + c];
    h1[c] = fmaxf(acc, 0.f);
    __syncthreads();
    acc = bc2[c];
    for (int k = 0; k < HID; k++) acc += h1[k] * Wc2[k * HID + c];
    h2[c] = fmaxf(acc, 0.f);
    __syncthreads();
    float t = h2[c] * Wc3[c];
    for (int off = 32; off > 0; off >>= 1) t += __shfl_down(t, off, 64);
    __shared__ float part[2];
    if ((c & 63) == 0) part[c >> 6] = t;
    __syncthreads();
    if (c == 0) out[g] = part[0] + part[1] + bc3[0];
}

// ---------------- launcher ----------------
extern "C" void kernel_launch(void* const* d_in, const int* in_sizes, int n_in,
                              void* d_out, int out_size, void* d_ws, size_t ws_size,
                              hipStream_t stream) {
    const float* X     = (const float*)d_in[0];
    const int*   batch = (const int*)d_in[1];
    const int*   e0 = (const int*)d_in[2];
    const int*   e1 = (const int*)d_in[3];
    const int*   e2 = (const int*)d_in[4];
    const int*   e3 = (const int*)d_in[5];
    const int*   e4 = (const int*)d_in[6];
    const float* W0    = (const float*)d_in[7];
    const float* root0 = (const float*)d_in[8];
    const float* b0    = (const float*)d_in[9];
    const float* Wl    = (const float*)d_in[10];
    const float* rootl = (const float*)d_in[11];
    const float* bl    = (const float*)d_in[12];
    const float* Wc1   = (const float*)d_in[13];
    const float* bc1   = (const float*)d_in[14];
    const float* Wc2   = (const float*)d_in[15];
    const float* bc2   = (const float*)d_in[16];
    const float* Wc3   = (const float*)d_in[17];
    const float* bc3   = (const float*)d_in[18];
    const int E = in_sizes[2] / 2;
    const int NE = R_REL * E;

    char* base = (char*)d_ws;
    size_t o = 0;
    auto carve = [&](size_t bytes) -> char* {
        char* p = base + o;
        o = (o + bytes + 255) & ~(size_t)255;
        return p;
    };
    unsigned short* Y    = (unsigned short*)carve((size_t)6 * NPAD * HID * 2);
    unsigned short* hA   = (unsigned short*)carve((size_t)NPAD * HID * 2);
    unsigned short* hB   = (unsigned short*)carve((size_t)NPAD * HID * 2);
    unsigned short* Xb   = (unsigned short*)carve((size_t)NPAD * KPAD0 * 2);
    int*   cnt    = (int*)carve((size_t)M5 * 4);
    float* invc   = (float*)carve((size_t)M5 * 4);
    int*   offsc  = (int*)carve((size_t)N_NODES * 4);
    int*   mstart = (int*)carve((size_t)(N_NODES + 1) * 4);
    int*   mcur   = (int*)carve((size_t)N_NODES * 4);
    int*   mrec   = (int*)carve((size_t)NE * 4);
    float* mw     = (float*)carve((size_t)NE * 4);
    int*   bsum   = (int*)carve(2048);
    float* pooled = (float*)carve((size_t)G_GRAPHS * HID * 4);
    short* Wt0    = (short*)carve((size_t)6 * 128 * KPAD0 * 2);
    short* Wtl    = (short*)carve((size_t)L_LAYERS * 6 * 128 * HID * 2);

    // ---- CSR build + casts ----
    hipMemsetAsync(cnt, 0, (size_t)M5 * 4, stream);
    hipMemsetAsync(pooled, 0, (size_t)G_GRAPHS * HID * 4, stream);
    int eg = (NE + 255) / 256;
    k_count<<<eg, 256, 0, stream>>>(e0, e1, e2, e3, e4, cnt, E);
    int nblk = (N_NODES + 1023) / 1024;   // 98
    k_scan1<<<nblk, 256, 0, stream>>>(cnt, offsc, bsum);
    k_scan2<<<1, 512, 0, stream>>>(bsum, nblk);
    k_scan3<<<(N_NODES + 255) / 256, 256, 0, stream>>>(offsc, bsum, mstart, mcur, cnt, invc);
    k_fill<<<eg, 256, 0, stream>>>(e0, e1, e2, e3, e4, mcur, invc, mrec, mw, E);
    k_castX<<<(NPAD * KPAD0 + 255) / 256, 256, 0, stream>>>(X, Xb);
    k_tw0<<<(6 * 128 * KPAD0 + 255) / 256, 256, 0, stream>>>(root0, W0, Wt0);
    k_twl<<<(L_LAYERS * 6 * 128 * HID + 255) / 256, 256, 0, stream>>>(rootl, Wl, Wtl);

    int ggrid = 8 * TPX * 6;              // 4704 blocks (xcd-swizzled)
    int agg_grid = (N_NODES + 3) / 4;

    // ---- layer 0 (K=192 padded) ----
    gemm_direct<KPAD0><<<ggrid, 256, 0, stream>>>(Xb, Wt0, Y);
    aggregate<<<agg_grid, 256, 0, stream>>>(Y, mstart, mrec, mw, b0, hA);

    // ---- layers 1..2 (K=128) ----
    unsigned short* hin = hA; unsigned short* hout = hB;
    for (int l = 0; l < L_LAYERS; l++) {
        gemm_direct<HID><<<ggrid, 256, 0, stream>>>(hin, Wtl + (size_t)l * 6 * 128 * HID, Y);
        aggregate<<<agg_grid, 256, 0, stream>>>(Y, mstart, mrec, mw, bl + (size_t)l * HID, hout);
        unsigned short* t = hin; hin = hout; hout = t;
    }

    // ---- readout ----
    k_pool<<<(N_NODES + 127) / 128, 128, 0, stream>>>(hin, batch, pooled);
    k_mlp<<<G_GRAPHS, 128, 0, stream>>>(pooled, batch, Wc1, bc1, Wc2, bc2, Wc3, bc3, (float*)d_out);
}